// Round 5
// baseline (385.691 us; speedup 1.0000x reference)
//
#include <hip/hip_runtime.h>

// LengthRegulator: out[b,d,m] = x[b, d, idx[b,m]] * path[b, idx[b,m], m]
// (path one-hot along text axis, idx sorted along m).
//
// Single fused kernel, one block per (b, 256-mel tile):
//  Phase 1: per-column one-hot search. idx[m] is the m-th order statistic of
//           4096 uniforms over [0,512) => idx[m] ~ m/8, sigma ~4 rows. Scan
//           from wave-uniform (m/8 - 24) in groups of 16 outstanding loads;
//           full-rescan fallback keeps correctness for arbitrary input.
//           Publish idx/scale via 2 KB LDS.
//  Phase 2: wave-per-row streaming. Each lane owns 4 consecutive columns
//           (idx/scale cached in registers); per d-row: 4 clustered x gathers
//           (L1/L3-resident, ~3 lines/wave) + one coalesced 1 KB nt store.
// No workspace, no second launch, phase-1 latency of some blocks overlaps
// phase-2 store streaming of others.

#define BATCH   32
#define DIM     384
#define T_TEXT  512
#define T_MEL   4096
#define MTILE   256

typedef float nfloat4 __attribute__((ext_vector_type(4)));

__global__ __launch_bounds__(256) void length_regulator_fused(
    const float* __restrict__ x,      // [B, D, T_TEXT]
    const float* __restrict__ path,   // [B, T_TEXT, T_MEL]
    float* __restrict__ out)          // [B, D, T_MEL]
{
    const int mt = blockIdx.x;
    const int b  = blockIdx.y;
    const int t  = threadIdx.x;
    const int m  = mt * MTILE + t;

    __shared__ int   si[MTILE];
    __shared__ float ss[MTILE];

    // ---- Phase 1: find the one-hot row for column m ----------------------
    const float* pcol = path + (size_t)b * T_TEXT * T_MEL + m;
    int start = (m & ~63) / 8 - 24;    // wave-uniform, ~6 sigma below idx[m]
    if (start < 0) start = 0;

    int   idx   = 0;
    float scale = 0.0f;
    bool  found = false;

    for (int n = start; n < T_TEXT; n += 16) {
        float v[16];
        #pragma unroll
        for (int j = 0; j < 16; ++j) {
            const int row = n + j;
            v[j] = (row < T_TEXT) ? pcol[(size_t)row * T_MEL] : 0.0f;
        }
        #pragma unroll
        for (int j = 0; j < 16; ++j)
            if (v[j] != 0.0f) { idx = n + j; scale = v[j]; found = true; }
        if (__all(found)) break;       // idx sorted => wave's hits cluster
    }
    if (!__all(found)) {               // guaranteed-correct fallback
        for (int n = 0; n < T_TEXT; n += 16) {
            float v[16];
            #pragma unroll
            for (int j = 0; j < 16; ++j) {
                const int row = n + j;
                v[j] = (row < T_TEXT) ? pcol[(size_t)row * T_MEL] : 0.0f;
            }
            #pragma unroll
            for (int j = 0; j < 16; ++j)
                if (!found && v[j] != 0.0f) { idx = n + j; scale = v[j]; found = true; }
            if (__all(found)) break;
        }
    }
    si[t] = idx;
    ss[t] = scale;
    __syncthreads();

    // ---- Phase 2: stream 384 output rows, wave-per-row -------------------
    const int c  = (t & 63) * 4;       // 4 consecutive columns per lane
    const int r0 = t >> 6;             // wave id 0..3 = starting row
    const int i0 = si[c], i1 = si[c + 1], i2 = si[c + 2], i3 = si[c + 3];
    const float s0 = ss[c], s1 = ss[c + 1], s2 = ss[c + 2], s3 = ss[c + 3];

    const float* xb = x   + (size_t)b * DIM * T_TEXT;
    float*       ob = out + (size_t)b * DIM * T_MEL + (size_t)mt * MTILE + c;

    #pragma unroll 4
    for (int d = r0; d < DIM; d += 4) {
        const float* xr = xb + (size_t)d * T_TEXT;
        nfloat4 o;
        o.x = xr[i0] * s0;             // clustered gather: ~3 lines/wave, L1/L3 hot
        o.y = xr[i1] * s1;
        o.z = xr[i2] * s2;
        o.w = xr[i3] * s3;
        __builtin_nontemporal_store(o, (nfloat4*)(ob + (size_t)d * T_MEL));
    }
}

extern "C" void kernel_launch(void* const* d_in, const int* in_sizes, int n_in,
                              void* d_out, int out_size, void* d_ws, size_t ws_size,
                              hipStream_t stream) {
    (void)in_sizes; (void)n_in; (void)d_ws; (void)ws_size; (void)out_size;
    const float* x    = (const float*)d_in[0];   // [32, 384, 512]
    const float* path = (const float*)d_in[1];   // [32, 512, 4096]
    float*       out  = (float*)d_out;           // [32, 384, 4096]

    dim3 grid(T_MEL / MTILE, BATCH);             // (16, 32) = 512 blocks
    length_regulator_fused<<<grid, dim3(256), 0, stream>>>(x, path, out);
}

// Round 6
// 379.745 us; speedup vs baseline: 1.0157x; 1.0157x over previous
//
#include <hip/hip_runtime.h>

// LengthRegulator: out[b,d,m] = x[b, d, idx[b,m]] * path[b, idx[b,m], m]
// (path one-hot along text axis, idx sorted along m).
//
// Fused kernel, one block per (b, 256-mel tile), 512 blocks x 256 threads:
//  Phase 1: per-column one-hot search (order-statistic start m/8 - 24,
//           16 outstanding loads/group, full-rescan fallback). idx/scale
//           published via LDS; block [lo,hi] window via shfl+LDS reduce.
//  Phase 2: barrier-free per-wave software pipeline. Wave owns 96 rows in
//           6 chunks of 16. Per chunk: issue next chunk's 8 float4 global
//           staging loads -> emit 16 LDS-fed gather+nontemporal-store rows
//           (no vmem dependency => store pipe never stalls) -> ds_write the
//           staged regs into the wave's private double buffer. fillBuffer
//           proves ~6.5 TB/s needs only store-fed waves, not occupancy.
//  Fallback: if idx window exceeds WSTAGE (can't happen for sorted uniform
//           input, possible adversarially), use direct global gathers.

#define BATCH   32
#define DIM     384
#define T_TEXT  512
#define T_MEL   4096
#define MTILE   256
#define WSTAGE  128           // staged x window (floats), 512 B/row
#define CROWS   16            // rows per chunk per wave
#define WROWS   96            // rows per wave (DIM/4)

typedef float nfloat4 __attribute__((ext_vector_type(4)));

__global__ __launch_bounds__(256) void length_regulator_fused(
    const float* __restrict__ x,      // [B, D, T_TEXT]
    const float* __restrict__ path,   // [B, T_TEXT, T_MEL]
    float* __restrict__ out)          // [B, D, T_MEL]
{
    const int mt = blockIdx.x;
    const int b  = blockIdx.y;
    const int t  = threadIdx.x;
    const int m  = mt * MTILE + t;

    __shared__ float xstage[4 * 2 * CROWS * WSTAGE];  // 64 KB: per-wave double buffers
    __shared__ int   si[MTILE];
    __shared__ float ss[MTILE];
    __shared__ int   smin4[4], smax4[4];

    // ---- Phase 1: find the one-hot row for column m ----------------------
    const float* pcol = path + (size_t)b * T_TEXT * T_MEL + m;
    int start = (m & ~63) / 8 - 24;    // wave-uniform, ~6 sigma below idx[m]
    if (start < 0) start = 0;

    int   idx   = 0;
    float scale = 0.0f;
    bool  found = false;

    for (int n = start; n < T_TEXT; n += 16) {
        float v[16];
        #pragma unroll
        for (int j = 0; j < 16; ++j) {
            const int row = n + j;
            v[j] = (row < T_TEXT) ? pcol[(size_t)row * T_MEL] : 0.0f;
        }
        #pragma unroll
        for (int j = 0; j < 16; ++j)
            if (v[j] != 0.0f) { idx = n + j; scale = v[j]; found = true; }
        if (__all(found)) break;       // idx sorted => wave's hits cluster
    }
    if (!__all(found)) {               // guaranteed-correct fallback
        for (int n = 0; n < T_TEXT; n += 16) {
            float v[16];
            #pragma unroll
            for (int j = 0; j < 16; ++j) {
                const int row = n + j;
                v[j] = (row < T_TEXT) ? pcol[(size_t)row * T_MEL] : 0.0f;
            }
            #pragma unroll
            for (int j = 0; j < 16; ++j)
                if (!found && v[j] != 0.0f) { idx = n + j; scale = v[j]; found = true; }
            if (__all(found)) break;
        }
    }
    si[t] = idx;
    ss[t] = scale;

    // block-wide idx min/max (butterfly within wave, leaders to LDS)
    int wmin = idx, wmax = idx;
    #pragma unroll
    for (int off = 32; off; off >>= 1) {
        wmin = min(wmin, __shfl_xor(wmin, off));
        wmax = max(wmax, __shfl_xor(wmax, off));
    }
    const int w = t >> 6;              // wave id 0..3
    if ((t & 63) == 0) { smin4[w] = wmin; smax4[w] = wmax; }
    __syncthreads();

    const int lo_raw = min(min(smin4[0], smin4[1]), min(smin4[2], smin4[3]));
    const int hi     = max(max(smax4[0], smax4[1]), max(smax4[2], smax4[3]));
    int lo = lo_raw & ~3;                          // 16 B-align staging source
    if (lo > T_TEXT - WSTAGE) lo = T_TEXT - WSTAGE;
    const bool staged = (hi - lo) < WSTAGE;

    // ---- Phase 2 ---------------------------------------------------------
    const int   c  = (t & 63) * 4;     // 4 consecutive output columns per lane
    const int   l  = t & 63;
    const float s0 = ss[c], s1 = ss[c + 1], s2 = ss[c + 2], s3 = ss[c + 3];
    const float* xb = x   + (size_t)b * DIM * T_TEXT;
    float*       ob = out + (size_t)b * DIM * T_MEL + (size_t)mt * MTILE + c;

    if (staged) {
        const int i0 = si[c] - lo, i1 = si[c + 1] - lo,
                  i2 = si[c + 2] - lo, i3 = si[c + 3] - lo;
        float* xw = xstage + w * (2 * CROWS * WSTAGE);   // this wave's buffers
        const int R0 = w * WROWS;

        nfloat4 v[8];
        // prologue: stage chunk 0
        #pragma unroll
        for (int i = 0; i < 8; ++i) {
            const int e = i * 256 + l * 4;
            v[i] = *(const nfloat4*)(xb + (size_t)(R0 + (e >> 7)) * T_TEXT + lo + (e & 127));
        }
        #pragma unroll
        for (int i = 0; i < 8; ++i) {
            const int e = i * 256 + l * 4;
            *(nfloat4*)(xw + e) = v[i];
        }

        #pragma unroll
        for (int k = 0; k < WROWS / CROWS; ++k) {        // 6 chunks
            const float* bufc = xw + (k & 1) * (CROWS * WSTAGE);
            float*       bufn = xw + ((k + 1) & 1) * (CROWS * WSTAGE);
            // 1) issue next chunk's global loads (in flight during stores)
            if (k < WROWS / CROWS - 1) {
                #pragma unroll
                for (int i = 0; i < 8; ++i) {
                    const int e = i * 256 + l * 4;
                    v[i] = *(const nfloat4*)(xb + (size_t)(R0 + (k + 1) * CROWS + (e >> 7)) * T_TEXT
                                             + lo + (e & 127));
                }
            }
            // 2) 16 LDS-fed gather + nt-store rows, no vmem waits
            #pragma unroll
            for (int r = 0; r < CROWS; ++r) {
                const float* xsr = bufc + r * WSTAGE;
                nfloat4 o;
                o.x = xsr[i0] * s0;    // clustered idx -> LDS broadcast
                o.y = xsr[i1] * s1;
                o.z = xsr[i2] * s2;
                o.w = xsr[i3] * s3;
                __builtin_nontemporal_store(o, (nfloat4*)(ob + (size_t)(R0 + k * CROWS + r) * T_MEL));
            }
            // 3) commit next chunk to the other buffer (wave-private: no barrier)
            if (k < WROWS / CROWS - 1) {
                #pragma unroll
                for (int i = 0; i < 8; ++i) {
                    const int e = i * 256 + l * 4;
                    *(nfloat4*)(bufn + e) = v[i];
                }
            }
        }
    } else {
        // correctness fallback: direct global gathers (adversarial idx only)
        const int i0 = si[c], i1 = si[c + 1], i2 = si[c + 2], i3 = si[c + 3];
        #pragma unroll 4
        for (int d = w; d < DIM; d += 4) {
            const float* xr = xb + (size_t)d * T_TEXT;
            nfloat4 o;
            o.x = xr[i0] * s0;
            o.y = xr[i1] * s1;
            o.z = xr[i2] * s2;
            o.w = xr[i3] * s3;
            __builtin_nontemporal_store(o, (nfloat4*)(ob + (size_t)d * T_MEL));
        }
    }
}

extern "C" void kernel_launch(void* const* d_in, const int* in_sizes, int n_in,
                              void* d_out, int out_size, void* d_ws, size_t ws_size,
                              hipStream_t stream) {
    (void)in_sizes; (void)n_in; (void)d_ws; (void)ws_size; (void)out_size;
    const float* x    = (const float*)d_in[0];   // [32, 384, 512]
    const float* path = (const float*)d_in[1];   // [32, 512, 4096]
    float*       out  = (float*)d_out;           // [32, 384, 4096]

    dim3 grid(T_MEL / MTILE, BATCH);             // (16, 32) = 512 blocks
    length_regulator_fused<<<grid, dim3(256), 0, stream>>>(x, path, out);
}